// Round 3
// baseline (221.799 us; speedup 1.0000x reference)
//
#include <hip/hip_runtime.h>
#include <cstdint>

#define DIN 2048
#define ROWS 9
#define SCALE_F 0.35355339059327373f
#define EPS_F 1e-6f

// One block = 256 threads, grid-stride over positions (16 iters at 512 blocks).
// Thread t owns elements [8t, 8t+8) of every 2048-float row; its weight slice
// (64 consecutive floats of each row-major [2048][8] matrix) lives in VGPRs.
// Software-pipelined: next position's 18 row-loads are issued into the just-
// freed v0/v1 registers during the current position's compute, so VMEM stays
// busy across the (vmcnt-draining) barrier. One barrier per iteration;
// normalize+softmax+store runs entirely in wave 0 via shuffles against
// parity-double-buffered LDS partials while waves 1-3 run ahead.
__global__ __launch_bounds__(256, 2)
void router_kernel(const float* __restrict__ x, const float* __restrict__ bax,
                   const float* __restrict__ Wq, const float* __restrict__ bq,
                   const float* __restrict__ Wk, const float* __restrict__ bk,
                   float* __restrict__ out, int positions) {
    __shared__ float red[2][ROWS][4][8];   // [parity][row][wave][h] dot partials
    __shared__ float ssb[2][ROWS][4];      // [parity][row][wave] sumsq partials

    const int t = threadIdx.x;
    const int w = t >> 6;
    const int lane = t & 63;
    const int kn = lane >> 3;     // key index (wave-0 final phase)
    const int hh = lane & 7;      // hidden col (wave-0 final phase)

    // ---- preload weight slices (constant-indexed -> stays in VGPRs) ----
    float wqk[128];   // [0..63] = Wq slice, [64..127] = Wk slice
    {
        const float4* q4 = (const float4*)(Wq + 64 * t);
        const float4* k4 = (const float4*)(Wk + 64 * t);
#pragma unroll
        for (int j = 0; j < 16; ++j) {
            float4 a = q4[j];
            wqk[4 * j + 0] = a.x; wqk[4 * j + 1] = a.y;
            wqk[4 * j + 2] = a.z; wqk[4 * j + 3] = a.w;
        }
#pragma unroll
        for (int j = 0; j < 16; ++j) {
            float4 b = k4[j];
            wqk[64 + 4 * j + 0] = b.x; wqk[64 + 4 * j + 1] = b.y;
            wqk[64 + 4 * j + 2] = b.z; wqk[64 + 4 * j + 3] = b.w;
        }
    }
    const float kbias = bk[hh];
    const float qbias = bq[hh];

    const int stride = gridDim.x;
    long p = blockIdx.x;
    if (p >= positions) return;

    // ---- prologue: load first position's rows ----
    float4 v0[ROWS], v1[ROWS];
    {
        const float4* xr = (const float4*)(x + p * (long)DIN) + 2 * t;
        const float4* br = (const float4*)(bax + p * (long)(8 * DIN)) + 2 * t;
        v0[0] = xr[0];
        v1[0] = xr[1];
#pragma unroll
        for (int r = 1; r < ROWS; ++r) {
            v0[r] = br[(r - 1) * (DIN / 4)];
            v1[r] = br[(r - 1) * (DIN / 4) + 1];
        }
    }

    int buf = 0;
    for (; p < positions; p += stride, buf ^= 1) {
        // next-position pointers (clamped on last iter -> cached re-read, no HBM)
        const long pn = (p + stride < positions) ? (p + stride) : p;
        const float4* xr_n = (const float4*)(x + pn * (long)DIN) + 2 * t;
        const float4* br_n = (const float4*)(bax + pn * (long)(8 * DIN)) + 2 * t;

        float ssv[ROWS];
#pragma unroll
        for (int r = 0; r < ROWS; ++r) {
            const int base = (r == 0) ? 0 : 64;
            float e[8] = { v0[r].x, v0[r].y, v0[r].z, v0[r].w,
                           v1[r].x, v1[r].y, v1[r].z, v1[r].w };
            // prefetch next position's row r into the just-freed registers
            if (r == 0) { v0[0] = xr_n[0]; v1[0] = xr_n[1]; }
            else        { v0[r] = br_n[(r - 1) * (DIN / 4)];
                          v1[r] = br_n[(r - 1) * (DIN / 4) + 1]; }

            // sumsq partial
            float ss = e[0] * e[0];
#pragma unroll
            for (int j = 1; j < 8; ++j) ss = fmaf(e[j], e[j], ss);
            ssv[r] = ss;

            // dot partials for all 8 hidden cols over this thread's 8 elements
            float pd[8];
#pragma unroll
            for (int h = 0; h < 8; ++h) pd[h] = e[0] * wqk[base + h];
#pragma unroll
            for (int j = 1; j < 8; ++j)
#pragma unroll
                for (int h = 0; h < 8; ++h)
                    pd[h] = fmaf(e[j], wqk[base + 8 * j + h], pd[h]);

            // in-group-of-8 transpose reduce: 8 channels -> 1 per lane
            float r1[4];
#pragma unroll
            for (int i = 0; i < 4; ++i) {
                float keep = (lane & 1) ? pd[i + 4] : pd[i];
                float send = (lane & 1) ? pd[i] : pd[i + 4];
                r1[i] = keep + __shfl_xor(send, 1);
            }
            float r2[2];
#pragma unroll
            for (int i = 0; i < 2; ++i) {
                float keep = (lane & 2) ? r1[i + 2] : r1[i];
                float send = (lane & 2) ? r1[i] : r1[i + 2];
                r2[i] = keep + __shfl_xor(send, 2);
            }
            float keep = (lane & 4) ? r2[1] : r2[0];
            float send = (lane & 4) ? r2[0] : r2[1];
            float dv = keep + __shfl_xor(send, 4);
            dv += __shfl_xor(dv, 8);
            dv += __shfl_xor(dv, 16);
            dv += __shfl_xor(dv, 32);
            if (lane < 8)
                red[buf][r][w][((lane & 1) << 2) | (lane & 2) | ((lane & 4) >> 2)] = dv;
        }

        // ---- sumsq reduce: rows 0..7 via one transpose-reduce, row 8 alone ----
        {
            float r1[4];
#pragma unroll
            for (int i = 0; i < 4; ++i) {
                float keep = (lane & 1) ? ssv[i + 4] : ssv[i];
                float send = (lane & 1) ? ssv[i] : ssv[i + 4];
                r1[i] = keep + __shfl_xor(send, 1);
            }
            float r2[2];
#pragma unroll
            for (int i = 0; i < 2; ++i) {
                float keep = (lane & 2) ? r1[i + 2] : r1[i];
                float send = (lane & 2) ? r1[i] : r1[i + 2];
                r2[i] = keep + __shfl_xor(send, 2);
            }
            float keep = (lane & 4) ? r2[1] : r2[0];
            float send = (lane & 4) ? r2[0] : r2[1];
            float sv = keep + __shfl_xor(send, 4);
            sv += __shfl_xor(sv, 8);
            sv += __shfl_xor(sv, 16);
            sv += __shfl_xor(sv, 32);
            if (lane < 8)
                ssb[buf][((lane & 1) << 2) | (lane & 2) | ((lane & 4) >> 2)][w] = sv;
            float s8 = ssv[8];
#pragma unroll
            for (int m = 1; m < 64; m <<= 1) s8 += __shfl_xor(s8, m);
            if (lane == 0) ssb[buf][8][w] = s8;
        }

        __syncthreads();   // red[buf] + ssb[buf] visible; waves 1-3 run ahead after this

        // ---- wave 0: normalize + scores + softmax + store, all in-wave ----
        if (w == 0) {
            // key vector element k[kn][hh]
            float dtk = red[buf][kn + 1][0][hh] + red[buf][kn + 1][1][hh] +
                        red[buf][kn + 1][2][hh] + red[buf][kn + 1][3][hh];
            float ssk = ssb[buf][kn + 1][0] + ssb[buf][kn + 1][1] +
                        ssb[buf][kn + 1][2] + ssb[buf][kn + 1][3];
            float kval = fmaf(dtk, rsqrtf(ssk + EPS_F), kbias);
            // query element q[hh] (same for every group; computed in all lanes)
            float dtq = red[buf][0][0][hh] + red[buf][0][1][hh] +
                        red[buf][0][2][hh] + red[buf][0][3][hh];
            float ssq = ssb[buf][0][0] + ssb[buf][0][1] +
                        ssb[buf][0][2] + ssb[buf][0][3];
            float qval = fmaf(dtq, rsqrtf(ssq + EPS_F), qbias);
            // score_kn = SCALE * sum_h q[h]*k[kn][h]  (intra-group reduce)
            float s = qval * kval;
            s += __shfl_xor(s, 1);
            s += __shfl_xor(s, 2);
            s += __shfl_xor(s, 4);
            s *= SCALE_F;
            // softmax across the 8 groups (cross-group reduce)
            float mx = s;
            mx = fmaxf(mx, __shfl_xor(mx, 8));
            mx = fmaxf(mx, __shfl_xor(mx, 16));
            mx = fmaxf(mx, __shfl_xor(mx, 32));
            float ev = __expf(s - mx);
            float den = ev;
            den += __shfl_xor(den, 8);
            den += __shfl_xor(den, 16);
            den += __shfl_xor(den, 32);   // sums one value per group -> true denom
            if (hh == 0) out[p * 8 + kn] = ev / den;
        }
    }
}

extern "C" void kernel_launch(void* const* d_in, const int* in_sizes, int n_in,
                              void* d_out, int out_size, void* d_ws, size_t ws_size,
                              hipStream_t stream) {
    const float* x   = (const float*)d_in[0];
    const float* bax = (const float*)d_in[1];
    const float* Wq  = (const float*)d_in[2];
    const float* bq  = (const float*)d_in[3];
    const float* Wk  = (const float*)d_in[4];
    const float* bk  = (const float*)d_in[5];
    float* out = (float*)d_out;

    const int positions = in_sizes[0] / DIN;   // B*S
    int nb = positions < 512 ? positions : 512;
    router_kernel<<<nb, 256, 0, stream>>>(x, bax, Wq, bq, Wk, bk, out, positions);
}

// Round 4
// 120.735 us; speedup vs baseline: 1.8371x; 1.8371x over previous
//
#include <hip/hip_runtime.h>
#include <cstdint>

#define DIN 2048
#define ROWS 9
#define SCALE_F 0.35355339059327373f
#define EPS_F 1e-6f

// 512 threads/block, one block per position (grid-stride). Thread t owns
// elements [4t, 4t+4) of every 2048-float row; its weight slice (32
// consecutive floats of each row-major [2048][8] matrix) lives in VGPRs.
// Target: <=128 VGPR -> 4 waves/SIMD (2 blocks/CU), 2x the TLP of R1.
// Loads: 1 float4 per row per thread, 5-deep static prefetch (all indices
// compile-time). One barrier per iteration; normalize+softmax+store runs in
// wave 0 via shuffles against parity-double-buffered LDS partials while
// waves 1-7 run ahead into the next position.
__global__ __launch_bounds__(512, 4)
void router_kernel(const float* __restrict__ x, const float* __restrict__ bax,
                   const float* __restrict__ Wq, const float* __restrict__ bq,
                   const float* __restrict__ Wk, const float* __restrict__ bk,
                   float* __restrict__ out, int positions) {
    __shared__ float red[2][ROWS][8][9];   // [parity][row][wave][h(+pad)] dot partials
    __shared__ float ssb[2][ROWS][8];      // [parity][row][wave] sumsq partials

    const int t = threadIdx.x;    // 0..511
    const int w = t >> 6;         // wave 0..7
    const int lane = t & 63;
    const int kn = lane >> 3;     // key index (wave-0 tail)
    const int hh = lane & 7;      // hidden col (wave-0 tail)

    // ---- preload weight slices: rows [4t,4t+4) x 8 cols = 32 floats each ----
    float wq[32], wk[32];
    {
        const float4* q4 = (const float4*)(Wq + 32 * t);
        const float4* k4 = (const float4*)(Wk + 32 * t);
#pragma unroll
        for (int j = 0; j < 8; ++j) {
            float4 a = q4[j];
            wq[4 * j + 0] = a.x; wq[4 * j + 1] = a.y;
            wq[4 * j + 2] = a.z; wq[4 * j + 3] = a.w;
        }
#pragma unroll
        for (int j = 0; j < 8; ++j) {
            float4 b = k4[j];
            wk[4 * j + 0] = b.x; wk[4 * j + 1] = b.y;
            wk[4 * j + 2] = b.z; wk[4 * j + 3] = b.w;
        }
    }
    const float kbias = bk[hh];
    const float qbias = bq[hh];

    const int stride = gridDim.x;
    int buf = 0;
    for (long p = blockIdx.x; p < positions; p += stride, buf ^= 1) {
        const float4* xr = (const float4*)(x + p * (long)DIN) + t;
        const float4* br = (const float4*)(bax + p * (long)(8 * DIN)) + t;

        // ---- staggered loads: 5 up front, then 1 per row computed ----
        float4 v[ROWS];   // fully unrolled, compile-time indices only
#pragma unroll
        for (int r = 0; r < 5; ++r)
            v[r] = (r == 0) ? xr[0] : br[(r - 1) * (DIN / 4)];

        float ssv[ROWS];
#pragma unroll
        for (int r = 0; r < ROWS; ++r) {
            if (r < 4) v[r + 5] = br[(r + 4) * (DIN / 4)];

            float e[4] = { v[r].x, v[r].y, v[r].z, v[r].w };
            // sumsq partial
            ssv[r] = fmaf(e[3], e[3], fmaf(e[2], e[2], fmaf(e[1], e[1], e[0] * e[0])));

            // dot partials for all 8 hidden cols over this thread's 4 elements
            const float* wa = (r == 0) ? wq : wk;   // r is unroll-constant
            float pd[8];
#pragma unroll
            for (int h = 0; h < 8; ++h)
                pd[h] = fmaf(e[3], wa[24 + h],
                         fmaf(e[2], wa[16 + h],
                          fmaf(e[1], wa[8 + h], e[0] * wa[h])));

            // in-group-of-8 transpose reduce: 8 channels -> 1 per lane
            float r1[4];
#pragma unroll
            for (int i = 0; i < 4; ++i) {
                float keep = (lane & 1) ? pd[i + 4] : pd[i];
                float send = (lane & 1) ? pd[i] : pd[i + 4];
                r1[i] = keep + __shfl_xor(send, 1);
            }
            float r2[2];
#pragma unroll
            for (int i = 0; i < 2; ++i) {
                float keep = (lane & 2) ? r1[i + 2] : r1[i];
                float send = (lane & 2) ? r1[i] : r1[i + 2];
                r2[i] = keep + __shfl_xor(send, 2);
            }
            float keep = (lane & 4) ? r2[1] : r2[0];
            float send = (lane & 4) ? r2[0] : r2[1];
            float dv = keep + __shfl_xor(send, 4);
            // cross-group (8 groups per wave)
            dv += __shfl_xor(dv, 8);
            dv += __shfl_xor(dv, 16);
            dv += __shfl_xor(dv, 32);
            if (lane < 8)
                red[buf][r][w][((lane & 1) << 2) | (lane & 2) | ((lane & 4) >> 2)] = dv;
        }

        // ---- sumsq reduce: rows 0..7 via one transpose-reduce, row 8 alone ----
        {
            float r1[4];
#pragma unroll
            for (int i = 0; i < 4; ++i) {
                float keep = (lane & 1) ? ssv[i + 4] : ssv[i];
                float send = (lane & 1) ? ssv[i] : ssv[i + 4];
                r1[i] = keep + __shfl_xor(send, 1);
            }
            float r2[2];
#pragma unroll
            for (int i = 0; i < 2; ++i) {
                float keep = (lane & 2) ? r1[i + 2] : r1[i];
                float send = (lane & 2) ? r1[i] : r1[i + 2];
                r2[i] = keep + __shfl_xor(send, 2);
            }
            float keep = (lane & 4) ? r2[1] : r2[0];
            float send = (lane & 4) ? r2[0] : r2[1];
            float sv = keep + __shfl_xor(send, 4);
            sv += __shfl_xor(sv, 8);
            sv += __shfl_xor(sv, 16);
            sv += __shfl_xor(sv, 32);
            if (lane < 8)
                ssb[buf][((lane & 1) << 2) | (lane & 2) | ((lane & 4) >> 2)][w] = sv;
            float s8 = ssv[8];
#pragma unroll
            for (int m = 1; m < 64; m <<= 1) s8 += __shfl_xor(s8, m);
            if (lane == 0) ssb[buf][8][w] = s8;
        }

        __syncthreads();   // red[buf] + ssb[buf] visible; waves 1-7 run ahead

        // ---- wave 0: normalize + scores + softmax + store, all in-wave ----
        if (w == 0) {
            float dtk = 0.f, ssk = 0.f, dtq = 0.f, ssq = 0.f;
#pragma unroll
            for (int wv = 0; wv < 8; ++wv) {
                dtk += red[buf][kn + 1][wv][hh];
                ssk += ssb[buf][kn + 1][wv];
                dtq += red[buf][0][wv][hh];
                ssq += ssb[buf][0][wv];
            }
            float kval = fmaf(dtk, rsqrtf(ssk + EPS_F), kbias);
            float qval = fmaf(dtq, rsqrtf(ssq + EPS_F), qbias);
            // score_kn = SCALE * sum_h q[h]*k[kn][h]
            float s = qval * kval;
            s += __shfl_xor(s, 1);
            s += __shfl_xor(s, 2);
            s += __shfl_xor(s, 4);
            s *= SCALE_F;
            // softmax across the 8 groups
            float mx = s;
            mx = fmaxf(mx, __shfl_xor(mx, 8));
            mx = fmaxf(mx, __shfl_xor(mx, 16));
            mx = fmaxf(mx, __shfl_xor(mx, 32));
            float ev = __expf(s - mx);
            float den = ev;
            den += __shfl_xor(den, 8);
            den += __shfl_xor(den, 16);
            den += __shfl_xor(den, 32);
            if (hh == 0) out[p * 8 + kn] = ev / den;
        }
    }
}

extern "C" void kernel_launch(void* const* d_in, const int* in_sizes, int n_in,
                              void* d_out, int out_size, void* d_ws, size_t ws_size,
                              hipStream_t stream) {
    const float* x   = (const float*)d_in[0];
    const float* bax = (const float*)d_in[1];
    const float* Wq  = (const float*)d_in[2];
    const float* bq  = (const float*)d_in[3];
    const float* Wk  = (const float*)d_in[4];
    const float* bk  = (const float*)d_in[5];
    float* out = (float*)d_out;

    const int positions = in_sizes[0] / DIN;   // B*S
    int nb = positions < 512 ? positions : 512;
    router_kernel<<<nb, 512, 0, stream>>>(x, bax, Wq, bq, Wk, bk, out, positions);
}